// Round 4
// baseline (7373.050 us; speedup 1.0000x reference)
//
#include <hip/hip_runtime.h>
#include <hip/hip_bf16.h>

typedef __bf16 bf16;
typedef __bf16 bf16x8 __attribute__((ext_vector_type(8)));
typedef float f32x4 __attribute__((ext_vector_type(4)));

#define S_LEN 2048
#define D_MOD 512
#define NHEAD 8
#define DHEAD 64
#define NBATCH 2

// flags[1]: mask mode: 0 = 4-byte elems (int32/fp32), 1 = 1-byte, 2 = 2-byte (bf16)
__global__ void detect_kernel(const unsigned char* __restrict__ m, int* __restrict__ flags) {
    __shared__ int s4[4];
    int t = threadIdx.x;
    if (t < 4) s4[t] = 0;
    __syncthreads();
    int c3F = 0, c80p0 = 0, cnzo = 0;
    for (int i = t; i < 4096; i += 256) {
        unsigned b = m[i];
        c3F += (b == 0x3F);
        c80p0 += ((b == 0x80) && ((i & 3) == 0));
        cnzo += ((b != 0) && ((i & 3) != 0));
    }
    atomicAdd(&s4[1], c3F);
    atomicAdd(&s4[2], c80p0);
    atomicAdd(&s4[3], cnzo);
    __syncthreads();
    if (t == 0) {
        int mode;
        if (s4[1] > 0)      mode = (s4[2] > 0) ? 2 : 0;
        else if (s4[3] > 0) mode = 1;
        else                mode = 0;
        flags[1] = mode;
    }
}

__global__ void maskconv_kernel(const unsigned char* __restrict__ m,
                                const int* __restrict__ flags,
                                unsigned char* __restrict__ out) {
    long i = ((long)blockIdx.x * 256 + threadIdx.x) * 4;
    int mode = flags[1];
    uchar4 v;
    if (mode == 0) {
        const int* mi = (const int*)m;
        v.x = (unsigned char)(mi[i + 0] != 0);
        v.y = (unsigned char)(mi[i + 1] != 0);
        v.z = (unsigned char)(mi[i + 2] != 0);
        v.w = (unsigned char)(mi[i + 3] != 0);
    } else if (mode == 1) {
        uchar4 r = *(const uchar4*)(m + i);
        v.x = (r.x != 0); v.y = (r.y != 0); v.z = (r.z != 0); v.w = (r.w != 0);
    } else {
        const unsigned short* ms = (const unsigned short*)m;
        v.x = (unsigned char)(ms[i + 0] != 0);
        v.y = (unsigned char)(ms[i + 1] != 0);
        v.z = (unsigned char)(ms[i + 2] != 0);
        v.w = (unsigned char)(ms[i + 3] != 0);
    }
    *(uchar4*)(out + i) = v;
}

// ---------- naive fp32 GEMM: C[M,N] = A[M,K] @ W[K,N] + bias ----------
// EPI 0: plain fp32 ; EPI 1: relu fp32 ; EPI 2: + residual fp32
template<int EPI>
__global__ __launch_bounds__(256) void ngemm(
    const float* __restrict__ A, const float* __restrict__ W,
    const float* __restrict__ bias, const float* __restrict__ res,
    float* __restrict__ out, int M, int N, int K)
{
    __shared__ float As[64][17];
    __shared__ float Bs[16][65];
    int t = threadIdx.x;
    int tx = t & 15;   // n-dir
    int ty = t >> 4;   // m-dir
    int m0 = blockIdx.y * 64, n0 = blockIdx.x * 64;
    float acc[4][4] = {};

    for (int k0 = 0; k0 < K; k0 += 16) {
        __syncthreads();
        for (int i = t; i < 64 * 16; i += 256) {
            int r = i >> 4, c = i & 15;
            As[r][c] = A[(long)(m0 + r) * K + k0 + c];
        }
        for (int i = t; i < 16 * 64; i += 256) {
            int r = i >> 6, c = i & 63;
            Bs[r][c] = W[(long)(k0 + r) * N + n0 + c];
        }
        __syncthreads();
        #pragma unroll
        for (int kk = 0; kk < 16; ++kk) {
            float a[4], b[4];
            #pragma unroll
            for (int i = 0; i < 4; ++i) a[i] = As[ty * 4 + i][kk];
            #pragma unroll
            for (int j = 0; j < 4; ++j) b[j] = Bs[kk][tx * 4 + j];
            #pragma unroll
            for (int i = 0; i < 4; ++i)
                #pragma unroll
                for (int j = 0; j < 4; ++j)
                    acc[i][j] += a[i] * b[j];
        }
    }

    #pragma unroll
    for (int i = 0; i < 4; ++i)
    #pragma unroll
    for (int j = 0; j < 4; ++j) {
        int gm = m0 + ty * 4 + i;
        int gn = n0 + tx * 4 + j;
        long idx = (long)gm * N + gn;
        float v = acc[i][j] + bias[gn];
        if (EPI == 1) v = fmaxf(v, 0.f);
        if (EPI == 2) v += res[idx];
        out[idx] = v;
    }
}

// ---------- pack fp32 [B*S, H*64] -> bf16 [B,H,S,64] ----------
__global__ void pack_qk(const float* __restrict__ src, bf16* __restrict__ dst) {
    long idx = (long)blockIdx.x * 256 + threadIdx.x;
    int mrow = (int)(idx >> 9), n = (int)(idx & 511);
    int b = mrow >> 11, s = mrow & 2047, h = n >> 6, d = n & 63;
    dst[(((long)(b * NHEAD + h) * S_LEN + s) << 6) + d] = (bf16)src[idx];
}

// ---------- MFMA attention: exact two-pass softmax, writes fp32 probs ----------
__global__ __launch_bounds__(256) void attn_kernel(
    const bf16* __restrict__ Q, const bf16* __restrict__ Kg,
    const unsigned char* __restrict__ mask8,
    float* __restrict__ attnO)
{
    __shared__ bf16 Qs[64][72];
    __shared__ bf16 Ks[64][72];

    int t = threadIdx.x;
    int qt = blockIdx.x & 31, bh = blockIdx.x >> 5;
    int b_ = bh >> 3;
    int q0 = qt * 64;
    int lane = t & 63, wave = t >> 6;
    int lm = lane & 15, quad = lane >> 4, q8 = quad * 8;
    int sr = t >> 2, sc = (t & 3) * 16;

    const bf16* Qp = Q + (long)bh * (S_LEN * DHEAD) + (long)(q0 + sr) * DHEAD + sc;
    *(bf16x8*)&Qs[sr][sc]     = *(const bf16x8*)(Qp);
    *(bf16x8*)&Qs[sr][sc + 8] = *(const bf16x8*)(Qp + 8);

    float mrow[4], lrow[4];
    #pragma unroll
    for (int r = 0; r < 4; ++r) { mrow[r] = -1e30f; lrow[r] = 0.f; }

    const bf16* Kbase = Kg + (long)bh * (S_LEN * DHEAD);
    const unsigned char* Mbase = mask8 + (long)b_ * S_LEN * S_LEN;

    // pass 1: row max + sum(exp)
    for (int kt = 0; kt < 32; ++kt) {
        int k0 = kt * 64;
        __syncthreads();
        const bf16* Kp = Kbase + (long)(k0 + sr) * DHEAD + sc;
        *(bf16x8*)&Ks[sr][sc]     = *(const bf16x8*)(Kp);
        *(bf16x8*)&Ks[sr][sc + 8] = *(const bf16x8*)(Kp + 8);
        __syncthreads();

        f32x4 sacc[4] = {};
        bf16x8 a0 = *(const bf16x8*)&Qs[wave * 16 + lm][q8];
        bf16x8 a1 = *(const bf16x8*)&Qs[wave * 16 + lm][32 + q8];
        #pragma unroll
        for (int tn = 0; tn < 4; ++tn) {
            bf16x8 b0 = *(const bf16x8*)&Ks[tn * 16 + lm][q8];
            bf16x8 b1 = *(const bf16x8*)&Ks[tn * 16 + lm][32 + q8];
            sacc[tn] = __builtin_amdgcn_mfma_f32_16x16x32_bf16(a0, b0, sacc[tn], 0, 0, 0);
            sacc[tn] = __builtin_amdgcn_mfma_f32_16x16x32_bf16(a1, b1, sacc[tn], 0, 0, 0);
        }
        #pragma unroll
        for (int r = 0; r < 4; ++r) {
            int grow = q0 + wave * 16 + quad * 4 + r;
            const unsigned char* Mr = Mbase + (long)grow * S_LEN + k0 + lm;
            float sv[4];
            float tmax = -1e30f;
            #pragma unroll
            for (int tn = 0; tn < 4; ++tn) {
                float s = sacc[tn][r] * 0.125f;
                if (Mr[tn * 16]) s = -1e9f;
                sv[tn] = s;
                tmax = fmaxf(tmax, s);
            }
            #pragma unroll
            for (int off = 8; off; off >>= 1) tmax = fmaxf(tmax, __shfl_xor(tmax, off));
            float mnew = fmaxf(mrow[r], tmax);
            float es = 0.f;
            #pragma unroll
            for (int tn = 0; tn < 4; ++tn) es += __expf(sv[tn] - mnew);
            #pragma unroll
            for (int off = 8; off; off >>= 1) es += __shfl_xor(es, off);
            lrow[r] = lrow[r] * __expf(mrow[r] - mnew) + es;
            mrow[r] = mnew;
        }
    }
    float rl[4];
    #pragma unroll
    for (int r = 0; r < 4; ++r) rl[r] = 1.f / lrow[r];

    float* attnBase = attnO + (long)bh * S_LEN * S_LEN;

    // pass 2: recompute scores, write normalized probs (fp32)
    for (int kt = 0; kt < 32; ++kt) {
        int k0 = kt * 64;
        __syncthreads();
        const bf16* Kp = Kbase + (long)(k0 + sr) * DHEAD + sc;
        *(bf16x8*)&Ks[sr][sc]     = *(const bf16x8*)(Kp);
        *(bf16x8*)&Ks[sr][sc + 8] = *(const bf16x8*)(Kp + 8);
        __syncthreads();

        f32x4 sacc[4] = {};
        bf16x8 a0 = *(const bf16x8*)&Qs[wave * 16 + lm][q8];
        bf16x8 a1 = *(const bf16x8*)&Qs[wave * 16 + lm][32 + q8];
        #pragma unroll
        for (int tn = 0; tn < 4; ++tn) {
            bf16x8 b0 = *(const bf16x8*)&Ks[tn * 16 + lm][q8];
            bf16x8 b1 = *(const bf16x8*)&Ks[tn * 16 + lm][32 + q8];
            sacc[tn] = __builtin_amdgcn_mfma_f32_16x16x32_bf16(a0, b0, sacc[tn], 0, 0, 0);
            sacc[tn] = __builtin_amdgcn_mfma_f32_16x16x32_bf16(a1, b1, sacc[tn], 0, 0, 0);
        }
        #pragma unroll
        for (int r = 0; r < 4; ++r) {
            int grow = q0 + wave * 16 + quad * 4 + r;
            const unsigned char* Mr = Mbase + (long)grow * S_LEN + k0 + lm;
            #pragma unroll
            for (int tn = 0; tn < 4; ++tn) {
                float s = sacc[tn][r] * 0.125f;
                if (Mr[tn * 16]) s = -1e9f;
                attnBase[(long)grow * S_LEN + k0 + tn * 16 + lm] = __expf(s - mrow[r]) * rl[r];
            }
        }
    }
}

// ---------- naive fp32 attention for context (one block per q-row) ----------
__global__ __launch_bounds__(256) void attn_naive(
    const float* __restrict__ qf, const float* __restrict__ kf,
    const float* __restrict__ vf, const unsigned char* __restrict__ mask8,
    float* __restrict__ ctxf)
{
    __shared__ float qv[64];
    __shared__ float pr[2048];
    __shared__ float red[256];
    int t = threadIdx.x;
    int bh = blockIdx.x >> 11;
    int qi = blockIdx.x & 2047;
    int b_ = bh >> 3, h_ = bh & 7;

    if (t < 64) qv[t] = qf[(long)(b_ * S_LEN + qi) * D_MOD + h_ * 64 + t];
    __syncthreads();

    const unsigned char* Mr = mask8 + (long)(b_ * S_LEN + qi) * S_LEN;
    float sc[8];
    float mymax = -1e30f;
    #pragma unroll
    for (int c8 = 0; c8 < 8; ++c8) {
        int c = c8 * 256 + t;
        const float4* kr = (const float4*)(kf + (long)(b_ * S_LEN + c) * D_MOD + h_ * 64);
        float s = 0.f;
        #pragma unroll
        for (int d4 = 0; d4 < 16; ++d4) {
            float4 kvv = kr[d4];
            s += qv[d4 * 4 + 0] * kvv.x + qv[d4 * 4 + 1] * kvv.y
               + qv[d4 * 4 + 2] * kvv.z + qv[d4 * 4 + 3] * kvv.w;
        }
        s *= 0.125f;
        if (Mr[c]) s = -1e9f;
        sc[c8] = s;
        mymax = fmaxf(mymax, s);
    }
    red[t] = mymax; __syncthreads();
    for (int st = 128; st; st >>= 1) {
        if (t < st) red[t] = fmaxf(red[t], red[t + st]);
        __syncthreads();
    }
    float bmax = red[0]; __syncthreads();

    float mysum = 0.f;
    #pragma unroll
    for (int c8 = 0; c8 < 8; ++c8) {
        float p = __expf(sc[c8] - bmax);
        pr[c8 * 256 + t] = p;
        mysum += p;
    }
    red[t] = mysum; __syncthreads();
    for (int st = 128; st; st >>= 1) {
        if (t < st) red[t] += red[t + st];
        __syncthreads();
    }
    float rinv = 1.f / red[0]; __syncthreads();

    int d = t & 63, seg = t >> 6;
    float o = 0.f;
    for (int c = seg * 512; c < seg * 512 + 512; ++c)
        o += pr[c] * vf[(long)(b_ * S_LEN + c) * D_MOD + h_ * 64 + d];
    red[t] = o; __syncthreads();
    if (t < 64) {
        float ov = red[t] + red[t + 64] + red[t + 128] + red[t + 192];
        ctxf[(long)(b_ * S_LEN + qi) * D_MOD + h_ * 64 + t] = ov * rinv;
    }
}

// ---------- layernorm over D=512, fp32 in / fp32 out ----------
__global__ __launch_bounds__(256) void ln_kernel(
    const float* __restrict__ X, const float* __restrict__ g,
    const float* __restrict__ bb, float* __restrict__ out)
{
    __shared__ float red[8];
    int row = blockIdx.x, t = threadIdx.x;
    float x0 = X[(long)row * 512 + t];
    float x1 = X[(long)row * 512 + 256 + t];
    float s = x0 + x1, ss = x0 * x0 + x1 * x1;
    #pragma unroll
    for (int off = 32; off; off >>= 1) { s += __shfl_xor(s, off); ss += __shfl_xor(ss, off); }
    if ((t & 63) == 0) { red[t >> 6] = s; red[4 + (t >> 6)] = ss; }
    __syncthreads();
    float S_ = red[0] + red[1] + red[2] + red[3];
    float SS = red[4] + red[5] + red[6] + red[7];
    float mu = S_ * (1.f / 512.f);
    float var = SS * (1.f / 512.f) - mu * mu;
    float is = rsqrtf(var + 1e-5f);
    out[(long)row * 512 + t]       = (x0 - mu) * is * g[t]       + bb[t];
    out[(long)row * 512 + 256 + t] = (x1 - mu) * is * g[t + 256] + bb[t + 256];
}

// ---------------- host launch ----------------
extern "C" void kernel_launch(void* const* d_in, const int* in_sizes, int n_in,
                              void* d_out, int out_size, void* d_ws, size_t ws_size,
                              hipStream_t stream)
{
    const float* x = (const float*)d_in[0];
    const unsigned char* maskraw = (const unsigned char*)d_in[1];
    const float* Wq = (const float*)d_in[2];  const float* bq = (const float*)d_in[3];
    const float* Wk = (const float*)d_in[4];  const float* bk = (const float*)d_in[5];
    const float* Wv = (const float*)d_in[6];  const float* bv = (const float*)d_in[7];
    const float* Wo = (const float*)d_in[8];  const float* bo = (const float*)d_in[9];
    const float* ln1g = (const float*)d_in[10]; const float* ln1b = (const float*)d_in[11];
    const float* W1 = (const float*)d_in[12]; const float* b1f = (const float*)d_in[13];
    const float* W2 = (const float*)d_in[14]; const float* b2f = (const float*)d_in[15];
    const float* ln2g = (const float*)d_in[16]; const float* ln2b = (const float*)d_in[17];

    // OUTPUTS ARE FP32: out [B*S*D] then attn [B*H*S*S], concatenated flat.
    float* outMain = (float*)d_out;
    float* outAttn = outMain + (size_t)NBATCH * S_LEN * D_MOD;

    char* w = (char*)d_ws;
    size_t off = 0;
    auto alloc = [&](size_t bytes) -> char* {
        char* p = w + off;
        off += (bytes + 255) & ~(size_t)255;
        return p;
    };
    const size_t MB = 1024 * 1024;
    int* flags = (int*)alloc(256);
    unsigned char* mask8 = (unsigned char*)alloc(8 * MB);
    // contiguous 32MB span {qf,kf,vf,ctxf}, later aliased by hbuf (fp32 4096x2048)
    float* qf   = (float*)alloc(8 * MB);
    float* kf   = (float*)alloc(8 * MB);
    float* vf   = (float*)alloc(8 * MB);
    float* ctxf = (float*)alloc(8 * MB);
    float* hbuf = qf;  // alias: written only after ctxf's last read
    float* tmp   = (float*)alloc(8 * MB);
    float* aoutf = (float*)alloc(8 * MB);
    bf16* Qb   = (bf16*)alloc(4 * MB);
    bf16* Kb   = (bf16*)alloc(4 * MB);

    const int M = NBATCH * S_LEN;  // 4096

    detect_kernel<<<1, 256, 0, stream>>>(maskraw, flags);
    maskconv_kernel<<<(NBATCH * S_LEN * S_LEN) / 1024, 256, 0, stream>>>(maskraw, flags, mask8);

    // QKV projections (naive fp32, weights read natively [K,N])
    ngemm<0><<<dim3(8, 64), 256, 0, stream>>>(x, Wq, bq, nullptr, qf, M, 512, 512);
    ngemm<0><<<dim3(8, 64), 256, 0, stream>>>(x, Wk, bk, nullptr, kf, M, 512, 512);
    ngemm<0><<<dim3(8, 64), 256, 0, stream>>>(x, Wv, bv, nullptr, vf, M, 512, 512);

    // bf16 packs for the MFMA probs kernel
    pack_qk<<<(M * 512) / 256, 256, 0, stream>>>(qf, Qb);
    pack_qk<<<(M * 512) / 256, 256, 0, stream>>>(kf, Kb);

    // MFMA attention: writes fp32 attn probs (Output 1)
    attn_kernel<<<512, 256, 0, stream>>>(Qb, Kb, mask8, outAttn);

    // naive fp32 attention: context for the out path (Output 0)
    attn_naive<<<NBATCH * NHEAD * S_LEN, 256, 0, stream>>>(qf, kf, vf, mask8, ctxf);

    // out-proj + residual + LN1
    ngemm<2><<<dim3(8, 64), 256, 0, stream>>>(ctxf, Wo, bo, x, tmp, M, 512, 512);
    ln_kernel<<<M, 256, 0, stream>>>(tmp, ln1g, ln1b, aoutf);

    // FFN (hbuf aliases qf..ctxf span — all consumed above)
    ngemm<1><<<dim3(32, 64), 256, 0, stream>>>(aoutf, W1, b1f, nullptr, hbuf, M, 2048, 512);
    ngemm<2><<<dim3(8, 64), 256, 0, stream>>>(hbuf, W2, b2f, aoutf, tmp, M, 512, 2048);
    ln_kernel<<<M, 256, 0, stream>>>(tmp, ln2g, ln2b, outMain);

    (void)in_sizes; (void)n_in; (void)out_size; (void)ws_size;
}

// Round 5
// 1530.524 us; speedup vs baseline: 4.8173x; 4.8173x over previous
//
#include <hip/hip_runtime.h>
#include <hip/hip_bf16.h>

typedef __bf16 bf16;
typedef __bf16 bf16x8 __attribute__((ext_vector_type(8)));
typedef float f32x4 __attribute__((ext_vector_type(4)));

#define S_LEN 2048
#define D_MOD 512
#define NHEAD 8
#define DHEAD 64
#define NBATCH 2

// flags[1]: mask mode: 0 = 4-byte elems (int32/fp32), 1 = 1-byte, 2 = 2-byte (bf16)
__global__ void detect_kernel(const unsigned char* __restrict__ m, int* __restrict__ flags) {
    __shared__ int s4[4];
    int t = threadIdx.x;
    if (t < 4) s4[t] = 0;
    __syncthreads();
    int c3F = 0, c80p0 = 0, cnzo = 0;
    for (int i = t; i < 4096; i += 256) {
        unsigned b = m[i];
        c3F += (b == 0x3F);
        c80p0 += ((b == 0x80) && ((i & 3) == 0));
        cnzo += ((b != 0) && ((i & 3) != 0));
    }
    atomicAdd(&s4[1], c3F);
    atomicAdd(&s4[2], c80p0);
    atomicAdd(&s4[3], cnzo);
    __syncthreads();
    if (t == 0) {
        int mode;
        if (s4[1] > 0)      mode = (s4[2] > 0) ? 2 : 0;
        else if (s4[3] > 0) mode = 1;
        else                mode = 0;
        flags[1] = mode;
    }
}

__global__ void maskconv_kernel(const unsigned char* __restrict__ m,
                                const int* __restrict__ flags,
                                unsigned char* __restrict__ out) {
    long i = ((long)blockIdx.x * 256 + threadIdx.x) * 4;
    int mode = flags[1];
    uchar4 v;
    if (mode == 0) {
        const int* mi = (const int*)m;
        v.x = (unsigned char)(mi[i + 0] != 0);
        v.y = (unsigned char)(mi[i + 1] != 0);
        v.z = (unsigned char)(mi[i + 2] != 0);
        v.w = (unsigned char)(mi[i + 3] != 0);
    } else if (mode == 1) {
        uchar4 r = *(const uchar4*)(m + i);
        v.x = (r.x != 0); v.y = (r.y != 0); v.z = (r.z != 0); v.w = (r.w != 0);
    } else {
        const unsigned short* ms = (const unsigned short*)m;
        v.x = (unsigned char)(ms[i + 0] != 0);
        v.y = (unsigned char)(ms[i + 1] != 0);
        v.z = (unsigned char)(ms[i + 2] != 0);
        v.w = (unsigned char)(ms[i + 3] != 0);
    }
    *(uchar4*)(out + i) = v;
}

// ---------- naive fp32 GEMM: C[M,N] = A[M,K] @ W[K,N] + bias ----------
// EPI 0: plain fp32 ; EPI 1: relu fp32 ; EPI 2: + residual fp32
template<int EPI>
__global__ __launch_bounds__(256) void ngemm(
    const float* __restrict__ A, const float* __restrict__ W,
    const float* __restrict__ bias, const float* __restrict__ res,
    float* __restrict__ out, int M, int N, int K)
{
    __shared__ float As[64][17];
    __shared__ float Bs[16][65];
    int t = threadIdx.x;
    int tx = t & 15;   // n-dir
    int ty = t >> 4;   // m-dir
    int m0 = blockIdx.y * 64, n0 = blockIdx.x * 64;
    float acc[4][4] = {};

    for (int k0 = 0; k0 < K; k0 += 16) {
        __syncthreads();
        for (int i = t; i < 64 * 16; i += 256) {
            int r = i >> 4, c = i & 15;
            As[r][c] = A[(long)(m0 + r) * K + k0 + c];
        }
        for (int i = t; i < 16 * 64; i += 256) {
            int r = i >> 6, c = i & 63;
            Bs[r][c] = W[(long)(k0 + r) * N + n0 + c];
        }
        __syncthreads();
        #pragma unroll
        for (int kk = 0; kk < 16; ++kk) {
            float a[4], b[4];
            #pragma unroll
            for (int i = 0; i < 4; ++i) a[i] = As[ty * 4 + i][kk];
            #pragma unroll
            for (int j = 0; j < 4; ++j) b[j] = Bs[kk][tx * 4 + j];
            #pragma unroll
            for (int i = 0; i < 4; ++i)
                #pragma unroll
                for (int j = 0; j < 4; ++j)
                    acc[i][j] += a[i] * b[j];
        }
    }

    #pragma unroll
    for (int i = 0; i < 4; ++i)
    #pragma unroll
    for (int j = 0; j < 4; ++j) {
        int gm = m0 + ty * 4 + i;
        int gn = n0 + tx * 4 + j;
        long idx = (long)gm * N + gn;
        float v = acc[i][j] + bias[gn];
        if (EPI == 1) v = fmaxf(v, 0.f);
        if (EPI == 2) v += res[idx];
        out[idx] = v;
    }
}

// ---------- pack fp32 [B*S, H*64] -> bf16 [B,H,S,64] ----------
__global__ void pack_qk(const float* __restrict__ src, bf16* __restrict__ dst) {
    long idx = (long)blockIdx.x * 256 + threadIdx.x;
    int mrow = (int)(idx >> 9), n = (int)(idx & 511);
    int b = mrow >> 11, s = mrow & 2047, h = n >> 6, d = n & 63;
    dst[(((long)(b * NHEAD + h) * S_LEN + s) << 6) + d] = (bf16)src[idx];
}
// ---------- pack fp32 [B*S, H*64] -> bf16 [B,H,64,S] (V^T) ----------
__global__ void pack_v(const float* __restrict__ src, bf16* __restrict__ dst) {
    long idx = (long)blockIdx.x * 256 + threadIdx.x;
    int mrow = (int)(idx >> 9), n = (int)(idx & 511);
    int b = mrow >> 11, s = mrow & 2047, h = n >> 6, d = n & 63;
    dst[(((long)(b * NHEAD + h) * DHEAD + d) << 11) + s] = (bf16)src[idx];
}

// ---------- MFMA attention: two-pass softmax; fp32 probs + fp32 ctx ----------
__global__ __launch_bounds__(256) void attn_kernel(
    const bf16* __restrict__ Q, const bf16* __restrict__ Kg,
    const bf16* __restrict__ Vt, const unsigned char* __restrict__ mask8,
    float* __restrict__ attnO, float* __restrict__ ctxf)
{
    __shared__ bf16 Qs[64][72];
    __shared__ bf16 Ks[64][72];
    __shared__ bf16 Vs[64][72];
    __shared__ bf16 Ps[64][72];

    int t = threadIdx.x;
    int qt = blockIdx.x & 31, bh = blockIdx.x >> 5;
    int b_ = bh >> 3, h_ = bh & 7;
    int q0 = qt * 64;
    int lane = t & 63, wave = t >> 6;
    int lm = lane & 15, quad = lane >> 4, q8 = quad * 8;
    int sr = t >> 2, sc = (t & 3) * 16;

    const bf16* Qp = Q + (long)bh * (S_LEN * DHEAD) + (long)(q0 + sr) * DHEAD + sc;
    *(bf16x8*)&Qs[sr][sc]     = *(const bf16x8*)(Qp);
    *(bf16x8*)&Qs[sr][sc + 8] = *(const bf16x8*)(Qp + 8);

    float mrow[4], lrow[4];
    #pragma unroll
    for (int r = 0; r < 4; ++r) { mrow[r] = -1e30f; lrow[r] = 0.f; }

    const bf16* Kbase = Kg + (long)bh * (S_LEN * DHEAD);
    const unsigned char* Mbase = mask8 + (long)b_ * S_LEN * S_LEN;

    // pass 1: row max + sum(exp)
    for (int kt = 0; kt < 32; ++kt) {
        int k0 = kt * 64;
        __syncthreads();
        const bf16* Kp = Kbase + (long)(k0 + sr) * DHEAD + sc;
        *(bf16x8*)&Ks[sr][sc]     = *(const bf16x8*)(Kp);
        *(bf16x8*)&Ks[sr][sc + 8] = *(const bf16x8*)(Kp + 8);
        __syncthreads();

        f32x4 sacc[4] = {};
        bf16x8 a0 = *(const bf16x8*)&Qs[wave * 16 + lm][q8];
        bf16x8 a1 = *(const bf16x8*)&Qs[wave * 16 + lm][32 + q8];
        #pragma unroll
        for (int tn = 0; tn < 4; ++tn) {
            bf16x8 b0 = *(const bf16x8*)&Ks[tn * 16 + lm][q8];
            bf16x8 b1 = *(const bf16x8*)&Ks[tn * 16 + lm][32 + q8];
            sacc[tn] = __builtin_amdgcn_mfma_f32_16x16x32_bf16(a0, b0, sacc[tn], 0, 0, 0);
            sacc[tn] = __builtin_amdgcn_mfma_f32_16x16x32_bf16(a1, b1, sacc[tn], 0, 0, 0);
        }
        #pragma unroll
        for (int r = 0; r < 4; ++r) {
            int grow = q0 + wave * 16 + quad * 4 + r;
            const unsigned char* Mr = Mbase + (long)grow * S_LEN + k0 + lm;
            float sv[4];
            float tmax = -1e30f;
            #pragma unroll
            for (int tn = 0; tn < 4; ++tn) {
                float s = sacc[tn][r] * 0.125f;
                if (Mr[tn * 16]) s = -1e9f;
                sv[tn] = s;
                tmax = fmaxf(tmax, s);
            }
            #pragma unroll
            for (int off = 8; off; off >>= 1) tmax = fmaxf(tmax, __shfl_xor(tmax, off));
            float mnew = fmaxf(mrow[r], tmax);
            float es = 0.f;
            #pragma unroll
            for (int tn = 0; tn < 4; ++tn) es += __expf(sv[tn] - mnew);
            #pragma unroll
            for (int off = 8; off; off >>= 1) es += __shfl_xor(es, off);
            lrow[r] = lrow[r] * __expf(mrow[r] - mnew) + es;
            mrow[r] = mnew;
        }
    }
    float rl[4];
    #pragma unroll
    for (int r = 0; r < 4; ++r) rl[r] = 1.f / lrow[r];

    float* attnBase = attnO + (long)bh * S_LEN * S_LEN;
    const bf16* Vbase = Vt + (long)bh * (DHEAD * S_LEN);
    f32x4 oacc[4] = {};

    // pass 2: recompute scores, write fp32 probs, accumulate PV
    for (int kt = 0; kt < 32; ++kt) {
        int k0 = kt * 64;
        __syncthreads();
        const bf16* Kp = Kbase + (long)(k0 + sr) * DHEAD + sc;
        *(bf16x8*)&Ks[sr][sc]     = *(const bf16x8*)(Kp);
        *(bf16x8*)&Ks[sr][sc + 8] = *(const bf16x8*)(Kp + 8);
        const bf16* Vp = Vbase + (long)sr * S_LEN + k0 + sc;
        *(bf16x8*)&Vs[sr][sc]     = *(const bf16x8*)(Vp);
        *(bf16x8*)&Vs[sr][sc + 8] = *(const bf16x8*)(Vp + 8);
        __syncthreads();

        f32x4 sacc[4] = {};
        bf16x8 a0 = *(const bf16x8*)&Qs[wave * 16 + lm][q8];
        bf16x8 a1 = *(const bf16x8*)&Qs[wave * 16 + lm][32 + q8];
        #pragma unroll
        for (int tn = 0; tn < 4; ++tn) {
            bf16x8 b0 = *(const bf16x8*)&Ks[tn * 16 + lm][q8];
            bf16x8 b1 = *(const bf16x8*)&Ks[tn * 16 + lm][32 + q8];
            sacc[tn] = __builtin_amdgcn_mfma_f32_16x16x32_bf16(a0, b0, sacc[tn], 0, 0, 0);
            sacc[tn] = __builtin_amdgcn_mfma_f32_16x16x32_bf16(a1, b1, sacc[tn], 0, 0, 0);
        }
        #pragma unroll
        for (int r = 0; r < 4; ++r) {
            int grow = q0 + wave * 16 + quad * 4 + r;
            const unsigned char* Mr = Mbase + (long)grow * S_LEN + k0 + lm;
            #pragma unroll
            for (int tn = 0; tn < 4; ++tn) {
                float s = sacc[tn][r] * 0.125f;
                if (Mr[tn * 16]) s = -1e9f;
                float p = __expf(s - mrow[r]) * rl[r];
                attnBase[(long)grow * S_LEN + k0 + tn * 16 + lm] = p;
                Ps[wave * 16 + quad * 4 + r][tn * 16 + lm] = (bf16)p;
            }
        }
        __syncthreads();
        bf16x8 pa0 = *(const bf16x8*)&Ps[wave * 16 + lm][q8];
        bf16x8 pa1 = *(const bf16x8*)&Ps[wave * 16 + lm][32 + q8];
        #pragma unroll
        for (int td = 0; td < 4; ++td) {
            bf16x8 v0 = *(const bf16x8*)&Vs[td * 16 + lm][q8];
            bf16x8 v1 = *(const bf16x8*)&Vs[td * 16 + lm][32 + q8];
            oacc[td] = __builtin_amdgcn_mfma_f32_16x16x32_bf16(pa0, v0, oacc[td], 0, 0, 0);
            oacc[td] = __builtin_amdgcn_mfma_f32_16x16x32_bf16(pa1, v1, oacc[td], 0, 0, 0);
        }
    }

    // ctx fp32 [B*S, H*64]
    #pragma unroll
    for (int td = 0; td < 4; ++td)
    #pragma unroll
    for (int r = 0; r < 4; ++r) {
        int grow = q0 + wave * 16 + quad * 4 + r;
        ctxf[(long)(b_ * S_LEN + grow) * D_MOD + h_ * 64 + td * 16 + lm] = oacc[td][r];
    }
}

// ---------- layernorm over D=512, fp32 in / fp32 out ----------
__global__ __launch_bounds__(256) void ln_kernel(
    const float* __restrict__ X, const float* __restrict__ g,
    const float* __restrict__ bb, float* __restrict__ out)
{
    __shared__ float red[8];
    int row = blockIdx.x, t = threadIdx.x;
    float x0 = X[(long)row * 512 + t];
    float x1 = X[(long)row * 512 + 256 + t];
    float s = x0 + x1, ss = x0 * x0 + x1 * x1;
    #pragma unroll
    for (int off = 32; off; off >>= 1) { s += __shfl_xor(s, off); ss += __shfl_xor(ss, off); }
    if ((t & 63) == 0) { red[t >> 6] = s; red[4 + (t >> 6)] = ss; }
    __syncthreads();
    float S_ = red[0] + red[1] + red[2] + red[3];
    float SS = red[4] + red[5] + red[6] + red[7];
    float mu = S_ * (1.f / 512.f);
    float var = SS * (1.f / 512.f) - mu * mu;
    float is = rsqrtf(var + 1e-5f);
    out[(long)row * 512 + t]       = (x0 - mu) * is * g[t]       + bb[t];
    out[(long)row * 512 + 256 + t] = (x1 - mu) * is * g[t + 256] + bb[t + 256];
}

// ---------------- host launch ----------------
extern "C" void kernel_launch(void* const* d_in, const int* in_sizes, int n_in,
                              void* d_out, int out_size, void* d_ws, size_t ws_size,
                              hipStream_t stream)
{
    const float* x = (const float*)d_in[0];
    const unsigned char* maskraw = (const unsigned char*)d_in[1];
    const float* Wq = (const float*)d_in[2];  const float* bq = (const float*)d_in[3];
    const float* Wk = (const float*)d_in[4];  const float* bk = (const float*)d_in[5];
    const float* Wv = (const float*)d_in[6];  const float* bv = (const float*)d_in[7];
    const float* Wo = (const float*)d_in[8];  const float* bo = (const float*)d_in[9];
    const float* ln1g = (const float*)d_in[10]; const float* ln1b = (const float*)d_in[11];
    const float* W1 = (const float*)d_in[12]; const float* b1f = (const float*)d_in[13];
    const float* W2 = (const float*)d_in[14]; const float* b2f = (const float*)d_in[15];
    const float* ln2g = (const float*)d_in[16]; const float* ln2b = (const float*)d_in[17];

    // OUTPUTS ARE FP32: out [B*S*D] then attn [B*H*S*S], concatenated flat.
    float* outMain = (float*)d_out;
    float* outAttn = outMain + (size_t)NBATCH * S_LEN * D_MOD;

    char* w = (char*)d_ws;
    size_t off = 0;
    auto alloc = [&](size_t bytes) -> char* {
        char* p = w + off;
        off += (bytes + 255) & ~(size_t)255;
        return p;
    };
    const size_t MB = 1024 * 1024;
    int* flags = (int*)alloc(256);
    unsigned char* mask8 = (unsigned char*)alloc(8 * MB);
    // contiguous 32MB span {qf,kf,vf,ctxf}, later aliased by hbuf (fp32 4096x2048)
    float* qf   = (float*)alloc(8 * MB);
    float* kf   = (float*)alloc(8 * MB);
    float* vf   = (float*)alloc(8 * MB);
    float* ctxf = (float*)alloc(8 * MB);
    float* hbuf = qf;  // alias: written only after ctxf's last read
    float* tmp   = (float*)alloc(8 * MB);
    float* aoutf = (float*)alloc(8 * MB);
    bf16* Qb   = (bf16*)alloc(4 * MB);
    bf16* Kb   = (bf16*)alloc(4 * MB);
    bf16* Vtb  = (bf16*)alloc(4 * MB);

    const int M = NBATCH * S_LEN;  // 4096

    detect_kernel<<<1, 256, 0, stream>>>(maskraw, flags);
    maskconv_kernel<<<(NBATCH * S_LEN * S_LEN) / 1024, 256, 0, stream>>>(maskraw, flags, mask8);

    // QKV projections (naive fp32, weights read natively [K,N])
    ngemm<0><<<dim3(8, 64), 256, 0, stream>>>(x, Wq, bq, nullptr, qf, M, 512, 512);
    ngemm<0><<<dim3(8, 64), 256, 0, stream>>>(x, Wk, bk, nullptr, kf, M, 512, 512);
    ngemm<0><<<dim3(8, 64), 256, 0, stream>>>(x, Wv, bv, nullptr, vf, M, 512, 512);

    // bf16 packs for MFMA attention
    pack_qk<<<(M * 512) / 256, 256, 0, stream>>>(qf, Qb);
    pack_qk<<<(M * 512) / 256, 256, 0, stream>>>(kf, Kb);
    pack_v<<<(M * 512) / 256, 256, 0, stream>>>(vf, Vtb);

    // fused MFMA attention: fp32 probs (Output 1) + fp32 context
    attn_kernel<<<512, 256, 0, stream>>>(Qb, Kb, Vtb, mask8, outAttn, ctxf);

    // out-proj + residual + LN1
    ngemm<2><<<dim3(8, 64), 256, 0, stream>>>(ctxf, Wo, bo, x, tmp, M, 512, 512);
    ln_kernel<<<M, 256, 0, stream>>>(tmp, ln1g, ln1b, aoutf);

    // FFN (hbuf aliases qf..ctxf span — all consumed above)
    ngemm<1><<<dim3(32, 64), 256, 0, stream>>>(aoutf, W1, b1f, nullptr, hbuf, M, 2048, 512);
    ngemm<2><<<dim3(8, 64), 256, 0, stream>>>(hbuf, W2, b2f, aoutf, tmp, M, 512, 2048);
    ln_kernel<<<M, 256, 0, stream>>>(tmp, ln2g, ln2b, outMain);

    (void)in_sizes; (void)n_in; (void)out_size; (void)ws_size;
}